// Round 11
// baseline (1062.705 us; speedup 1.0000x reference)
//
#include <hip/hip_runtime.h>
#include <hip/hip_bf16.h>
#include <math.h>

// ---------------------------------------------------------------------------
// MultiLayerGAT: 3x GATConv (PyG-style, self-loops added) + log_softmax.
// N=10000, E=320000; 128->8x32(elu) -> 256->8x32(elu) -> 256->40 -> log_softmax
//
// R10: single persistent megakernel (1024 blocks, __launch_bounds__(256,4) ->
// guaranteed 4 blocks/CU co-residency) with manual device-scope grid barriers
// between phases:
//   P0: zero cursor + prep (casts/transposes/al-folds)
//   P1: ELL atomic scatter + layer-1 GEMM (independent, co-phased)
//   P2: agg1   P3: GEMM2   P4: agg2   P5: GEMM3   P6: agg_out
// Phase bodies identical to R9 (numerics unchanged). Eliminates ~7 dispatch
// boundaries; adds 6 atomic-counter barriers (arrive=atomicAdd, spin until
// count >= nb*phase, __threadfence release/acquire for cross-XCD coherence).
// ---------------------------------------------------------------------------

#define DEV_INLINE __device__ __forceinline__

typedef __attribute__((ext_vector_type(8))) short short8;
typedef __attribute__((ext_vector_type(4))) float f32x4;
typedef unsigned short ushort_t;
typedef unsigned int uint_t;

#define ELLW 128
#define NB 1024   // persistent grid: 256 CU x 4 blocks/CU (launch_bounds-guaranteed)

DEV_INLINE float leaky02(float x) { return x > 0.f ? x : 0.2f * x; }
DEV_INLINE float elu1(float x) { return x > 0.f ? x : expm1f(x); }

DEV_INLINE ushort_t f2bf(float f) {
    uint_t u = __float_as_uint(f);
    u += 0x7FFFu + ((u >> 16) & 1u);
    return (ushort_t)(u >> 16);
}
DEV_INLINE float bf2f(ushort_t u) { return __uint_as_float(((uint_t)u) << 16); }

// ---------------- grid barrier (monotonic counter, device scope) -------------

DEV_INLINE void gsync(int* bar, int phase) {
    __syncthreads();
    if (threadIdx.x == 0) {
        __threadfence();   // release: flush this XCD's writes to device scope
        __hip_atomic_fetch_add(bar, 1, __ATOMIC_ACQ_REL, __HIP_MEMORY_SCOPE_AGENT);
        while (__hip_atomic_load(bar, __ATOMIC_ACQUIRE, __HIP_MEMORY_SCOPE_AGENT) < NB * phase) {
            __builtin_amdgcn_s_sleep(2);
        }
        __threadfence();   // acquire: invalidate stale lines before next phase
    }
    __syncthreads();
}

// ---------------- prep body: casts, transposes, al-weight folds --------------

DEV_INLINE void prep_body(int i,
                          const float* __restrict__ x, ushort_t* __restrict__ x_bf,
                          const float* __restrict__ W1, ushort_t* __restrict__ W1T,
                          const float* __restrict__ W2, ushort_t* __restrict__ W2T,
                          const float* __restrict__ W3, ushort_t* __restrict__ W3T,
                          const float* __restrict__ as1, const float* __restrict__ ad1,
                          const float* __restrict__ as2, const float* __restrict__ ad2,
                          const float* __restrict__ as3, const float* __restrict__ ad3,
                          int n) {
    int xcnt = n * 32;
    if (i < xcnt) {
        float4 v = *(const float4*)(x + (size_t)i * 4);
        ushort4 o;
        o.x = f2bf(v.x); o.y = f2bf(v.y); o.z = f2bf(v.z); o.w = f2bf(v.w);
        *(ushort4*)(x_bf + (size_t)i * 4) = o;
        return;
    }
    i -= xcnt;
    if (i < 128 * 256) {
        int k = i >> 8, c = i & 255;
        W1T[(size_t)c * 128 + k] = f2bf(W1[i]);
        return;
    }
    i -= 128 * 256;
    if (i < 256 * 256) {
        int k = i >> 8, c = i & 255;
        W2T[(size_t)c * 256 + k] = f2bf(W2[i]);
        return;
    }
    i -= 256 * 256;
    if (i < 256 * 40) {
        int k = i / 40, c = i - k * 40;
        W3T[(size_t)c * 256 + k] = f2bf(W3[i]);
        return;
    }
    i -= 256 * 40;
    if (i < 1024) {
        int h = i >> 7, k = i & 127;
        float acc = 0.f;
#pragma unroll
        for (int c = 0; c < 32; ++c) acc += W1[k * 256 + h * 32 + c] * as1[h * 32 + c];
        W1T[(size_t)(256 + h) * 128 + k] = f2bf(acc);
        return;
    }
    i -= 1024;
    if (i < 1024) {
        int h = i >> 7, k = i & 127;
        float acc = 0.f;
#pragma unroll
        for (int c = 0; c < 32; ++c) acc += W1[k * 256 + h * 32 + c] * ad1[h * 32 + c];
        W1T[(size_t)(264 + h) * 128 + k] = f2bf(acc);
        return;
    }
    i -= 1024;
    if (i < 2048) {
        int h = i >> 8, k = i & 255;
        float acc = 0.f;
#pragma unroll
        for (int c = 0; c < 32; ++c) acc += W2[k * 256 + h * 32 + c] * as2[h * 32 + c];
        W2T[(size_t)(256 + h) * 256 + k] = f2bf(acc);
        return;
    }
    i -= 2048;
    if (i < 2048) {
        int h = i >> 8, k = i & 255;
        float acc = 0.f;
#pragma unroll
        for (int c = 0; c < 32; ++c) acc += W2[k * 256 + h * 32 + c] * ad2[h * 32 + c];
        W2T[(size_t)(264 + h) * 256 + k] = f2bf(acc);
        return;
    }
    i -= 2048;
    if (i < 256) {
        float acc = 0.f;
#pragma unroll
        for (int c = 0; c < 40; ++c) acc += W3[i * 40 + c] * as3[c];
        W3T[(size_t)40 * 256 + i] = f2bf(acc);
        return;
    }
    i -= 256;
    if (i < 256) {
        float acc = 0.f;
#pragma unroll
        for (int c = 0; c < 40; ++c) acc += W3[i * 40 + c] * ad3[c];
        W3T[(size_t)41 * 256 + i] = f2bf(acc);
        return;
    }
}

// ---------------- ELL scatter body (one virtual block) -----------------------

DEV_INLINE void scatter_body(int vb, const int* __restrict__ src, const int* __restrict__ dst,
                             int* __restrict__ cursor, int* __restrict__ ell, int e) {
    int i4 = (vb * 256 + threadIdx.x) * 4;
    if (i4 + 3 < e) {
        int4 d = *(const int4*)(dst + i4);
        int4 s = *(const int4*)(src + i4);
        int p;
        p = atomicAdd(&cursor[d.x], 1); ell[d.x * ELLW + p] = s.x;
        p = atomicAdd(&cursor[d.y], 1); ell[d.y * ELLW + p] = s.y;
        p = atomicAdd(&cursor[d.z], 1); ell[d.z * ELLW + p] = s.z;
        p = atomicAdd(&cursor[d.w], 1); ell[d.w * ELLW + p] = s.w;
    } else {
        for (int k = i4; k < e; ++k) {
            int p = atomicAdd(&cursor[dst[k]], 1);
            ell[dst[k] * ELLW + p] = src[k];
        }
    }
}

// ---------------- MFMA GEMM body (cols >= NOUT routed to f32 als/ald) --------

DEV_INLINE int lds_slot(int r, int c) { return r * 4 + ((c + (r >> 1)) & 3); }

DEV_INLINE void gemm_body(ushort_t* __restrict__ As, ushort_t* __restrict__ Bs,
                          const ushort_t* __restrict__ A, const ushort_t* __restrict__ BT,
                          ushort_t* __restrict__ C, float* __restrict__ ALS,
                          float* __restrict__ ALD, int M, int NOUT, int NH, int NTOT,
                          int K, int bx, int by) {
    const int tid = threadIdx.x;
    const int wave = tid >> 6, lane = tid & 63;
    const int row0 = by * 64;
    const int col0 = bx * 64;

    const int sr = tid >> 2, sc = tid & 3;
    const int a_row = row0 + sr;
    const int b_row = col0 + sr;

    const int fr = lane & 15;
    const int fc = lane >> 4;

    f32x4 acc0 = {}, acc1 = {}, acc2 = {}, acc3 = {};

    for (int k0 = 0; k0 < K; k0 += 32) {
        short8 av = {}, bv = {};
        if (a_row < M) av = *(const short8*)(A + (size_t)a_row * K + k0 + sc * 8);
        if (b_row < NTOT) bv = *(const short8*)(BT + (size_t)b_row * K + k0 + sc * 8);
        __syncthreads();
        *(short8*)(As + lds_slot(sr, sc) * 8) = av;
        *(short8*)(Bs + lds_slot(sr, sc) * 8) = bv;
        __syncthreads();

        const int arow = wave * 16 + fr;
        short8 afrag = *(const short8*)(As + lds_slot(arow, fc) * 8);
        short8 b0 = *(const short8*)(Bs + lds_slot(0 * 16 + fr, fc) * 8);
        short8 b1 = *(const short8*)(Bs + lds_slot(1 * 16 + fr, fc) * 8);
        short8 b2 = *(const short8*)(Bs + lds_slot(2 * 16 + fr, fc) * 8);
        short8 b3 = *(const short8*)(Bs + lds_slot(3 * 16 + fr, fc) * 8);
        acc0 = __builtin_amdgcn_mfma_f32_16x16x32_bf16(afrag, b0, acc0, 0, 0, 0);
        acc1 = __builtin_amdgcn_mfma_f32_16x16x32_bf16(afrag, b1, acc1, 0, 0, 0);
        acc2 = __builtin_amdgcn_mfma_f32_16x16x32_bf16(afrag, b2, acc2, 0, 0, 0);
        acc3 = __builtin_amdgcn_mfma_f32_16x16x32_bf16(afrag, b3, acc3, 0, 0, 0);
    }
    __syncthreads();   // protect LDS reuse across grid-stride iterations

    const int crow = row0 + wave * 16 + (lane >> 4) * 4;
    const int ccol = col0 + (lane & 15);
    f32x4 accs[4] = {acc0, acc1, acc2, acc3};
#pragma unroll
    for (int ct = 0; ct < 4; ++ct) {
        int col = ccol + ct * 16;
#pragma unroll
        for (int j = 0; j < 4; ++j) {
            int row = crow + j;
            if (row >= M) continue;
            float v = accs[ct][j];
            if (col < NOUT) {
                C[(size_t)row * NOUT + col] = f2bf(v);
            } else {
                int cc = col - NOUT;
                if (cc < NH) ALS[(size_t)row * NH + cc] = v;
                else if (cc < 2 * NH) ALD[(size_t)row * NH + (cc - NH)] = v;
            }
        }
    }
}

// ---------------- aggregation node bodies (R9 inner loops) -------------------

DEV_INLINE void agg_h8_node(int node,
                            const ushort_t* __restrict__ xp, const float* __restrict__ als,
                            const float* __restrict__ ald, const int* __restrict__ degv,
                            const int* __restrict__ ell, const float* __restrict__ bias,
                            ushort_t* __restrict__ out) {
    const int lane = threadIdx.x & 63;
    const int half = lane >> 5;
    const int lh = lane & 31;
    const int ch = lh * 8;
    const int head = lh >> 2;
    const int deg = degv[node];
    const int rs = node * ELLW, re = rs + deg;
    const float ad = ald[node * 8 + head];
    const float m = leaky02(als[node * 8 + head] + ad);

    float acc[8];
    float ssum;
    if (half == 0) {
        short8 sv = *(const short8*)(xp + (size_t)node * 256 + ch);
#pragma unroll
        for (int i = 0; i < 8; ++i) acc[i] = bf2f((ushort_t)sv[i]);
        ssum = 1.0f;
    } else {
#pragma unroll
        for (int i = 0; i < 8; ++i) acc[i] = 0.f;
        ssum = 0.f;
    }

    for (int base = rs; base < re; base += 64) {
        const int cnt = (re - base < 64) ? (re - base) : 64;
        int myi = (lane < cnt) ? ell[base + lane] : 0;
        int j = 0;
        for (; j + 8 <= cnt; j += 8) {
            int s0 = __shfl(myi, j + half);
            int s1 = __shfl(myi, j + 2 + half);
            int s2 = __shfl(myi, j + 4 + half);
            int s3 = __shfl(myi, j + 6 + half);
            float a0 = als[s0 * 8 + head];
            float a1 = als[s1 * 8 + head];
            float a2 = als[s2 * 8 + head];
            float a3 = als[s3 * 8 + head];
            short8 v0 = *(const short8*)(xp + (size_t)s0 * 256 + ch);
            short8 v1 = *(const short8*)(xp + (size_t)s1 * 256 + ch);
            short8 v2 = *(const short8*)(xp + (size_t)s2 * 256 + ch);
            short8 v3 = *(const short8*)(xp + (size_t)s3 * 256 + ch);
            float p0 = __expf(leaky02(a0 + ad) - m);
            float p1 = __expf(leaky02(a1 + ad) - m);
            float p2 = __expf(leaky02(a2 + ad) - m);
            float p3 = __expf(leaky02(a3 + ad) - m);
            ssum += (p0 + p1) + (p2 + p3);
#pragma unroll
            for (int i = 0; i < 8; ++i)
                acc[i] += (p0 * bf2f((ushort_t)v0[i]) + p1 * bf2f((ushort_t)v1[i]))
                        + (p2 * bf2f((ushort_t)v2[i]) + p3 * bf2f((ushort_t)v3[i]));
        }
        for (; j < cnt; j += 2) {
            int jj = j + half;
            int s = __shfl(myi, jj & 63);
            bool valid = jj < cnt;
            float a = als[s * 8 + head];
            short8 v = *(const short8*)(xp + (size_t)s * 256 + ch);
            float p = valid ? __expf(leaky02(a + ad) - m) : 0.f;
            ssum += p;
#pragma unroll
            for (int i = 0; i < 8; ++i) acc[i] += p * bf2f((ushort_t)v[i]);
        }
    }

    ssum += __shfl_xor(ssum, 32);
#pragma unroll
    for (int i = 0; i < 8; ++i) acc[i] += __shfl_xor(acc[i], 32);

    if (half == 0) {
        float inv = 1.f / ssum;
        float4 ba = *(const float4*)(bias + ch);
        float4 bb = *(const float4*)(bias + ch + 4);
        float bv[8] = {ba.x, ba.y, ba.z, ba.w, bb.x, bb.y, bb.z, bb.w};
        short8 o;
#pragma unroll
        for (int i = 0; i < 8; ++i) o[i] = (short)f2bf(elu1(acc[i] * inv + bv[i]));
        *(short8*)(out + (size_t)node * 256 + ch) = o;
    }
}

DEV_INLINE void agg_out_node(int node,
                             const ushort_t* __restrict__ xp, const float* __restrict__ als,
                             const float* __restrict__ ald, const int* __restrict__ degv,
                             const int* __restrict__ ell, const float* __restrict__ bias,
                             float* __restrict__ out) {
    const int lane = threadIdx.x & 63;
    const int half = lane >> 5;
    const int lh = lane & 31;
    const bool act = lh < 20;
    const int ch = lh * 2;
    const int deg = degv[node];
    const int rs = node * ELLW, re = rs + deg;
    const float ad = ald[node];
    const float m = leaky02(als[node] + ad);

    float a0, a1, ssum;
    if (half == 0) {
        if (act) {
            ushort2 sv = *(const ushort2*)(xp + (size_t)node * 40 + ch);
            a0 = bf2f(sv.x); a1 = bf2f(sv.y);
        } else { a0 = a1 = 0.f; }
        ssum = 1.0f;
    } else { a0 = a1 = 0.f; ssum = 0.f; }

    for (int base = rs; base < re; base += 64) {
        const int cnt = (re - base < 64) ? (re - base) : 64;
        int myi = (lane < cnt) ? ell[base + lane] : 0;
        int j = 0;
        for (; j + 8 <= cnt; j += 8) {
            int s0 = __shfl(myi, j + half);
            int s1 = __shfl(myi, j + 2 + half);
            int s2 = __shfl(myi, j + 4 + half);
            int s3 = __shfl(myi, j + 6 + half);
            float e0 = als[s0];
            float e1 = als[s1];
            float e2 = als[s2];
            float e3 = als[s3];
            ushort2 v0 = act ? *(const ushort2*)(xp + (size_t)s0 * 40 + ch) : ushort2{0, 0};
            ushort2 v1 = act ? *(const ushort2*)(xp + (size_t)s1 * 40 + ch) : ushort2{0, 0};
            ushort2 v2 = act ? *(const ushort2*)(xp + (size_t)s2 * 40 + ch) : ushort2{0, 0};
            ushort2 v3 = act ? *(const ushort2*)(xp + (size_t)s3 * 40 + ch) : ushort2{0, 0};
            float p0 = __expf(leaky02(e0 + ad) - m);
            float p1 = __expf(leaky02(e1 + ad) - m);
            float p2 = __expf(leaky02(e2 + ad) - m);
            float p3 = __expf(leaky02(e3 + ad) - m);
            ssum += (p0 + p1) + (p2 + p3);
            a0 += (p0 * bf2f(v0.x) + p1 * bf2f(v1.x)) + (p2 * bf2f(v2.x) + p3 * bf2f(v3.x));
            a1 += (p0 * bf2f(v0.y) + p1 * bf2f(v1.y)) + (p2 * bf2f(v2.y) + p3 * bf2f(v3.y));
        }
        for (; j < cnt; j += 2) {
            int jj = j + half;
            int s = __shfl(myi, jj & 63);
            bool valid = jj < cnt;
            float a = als[s];
            ushort2 v = act ? *(const ushort2*)(xp + (size_t)s * 40 + ch) : ushort2{0, 0};
            float p = valid ? __expf(leaky02(a + ad) - m) : 0.f;
            ssum += p;
            a0 += p * bf2f(v.x);
            a1 += p * bf2f(v.y);
        }
    }

    ssum += __shfl_xor(ssum, 32);
    a0 += __shfl_xor(a0, 32);
    a1 += __shfl_xor(a1, 32);

    float inv = 1.f / ssum;
    float2 b2 = act ? *(const float2*)(bias + ch) : float2{0.f, 0.f};
    float o0 = act ? (a0 * inv + b2.x) : -INFINITY;
    float o1 = act ? (a1 * inv + b2.y) : -INFINITY;

    float mx = fmaxf(o0, o1);
#pragma unroll
    for (int off = 16; off >= 1; off >>= 1) mx = fmaxf(mx, __shfl_xor(mx, off));
    float ex = act ? (__expf(o0 - mx) + __expf(o1 - mx)) : 0.f;
#pragma unroll
    for (int off = 16; off >= 1; off >>= 1) ex += __shfl_xor(ex, off);
    float lse = mx + __logf(ex);
    if (half == 0 && act) {
        float2 o = {o0 - lse, o1 - lse};
        *(float2*)(out + (size_t)node * 40 + ch) = o;
    }
}

// ---------------- the megakernel ---------------------------------------------

__global__ __launch_bounds__(256, 4) void mega_kernel(
    const float* __restrict__ x, const int* __restrict__ edge,
    const float* __restrict__ W1, const float* __restrict__ as1,
    const float* __restrict__ ad1, const float* __restrict__ b1,
    const float* __restrict__ W2, const float* __restrict__ as2,
    const float* __restrict__ ad2, const float* __restrict__ b2,
    const float* __restrict__ W3, const float* __restrict__ as3,
    const float* __restrict__ ad3, const float* __restrict__ b3,
    float* __restrict__ out,
    ushort_t* __restrict__ xp, ushort_t* __restrict__ h_bf,
    ushort_t* __restrict__ xp3, ushort_t* __restrict__ x_bf,
    ushort_t* __restrict__ W1T, ushort_t* __restrict__ W2T, ushort_t* __restrict__ W3T,
    float* __restrict__ als, float* __restrict__ ald,
    int* __restrict__ cursor, int* __restrict__ ell, int* __restrict__ bar,
    int n, int e) {

    __shared__ ushort_t As[64 * 32];
    __shared__ ushort_t Bs[64 * 32];

    const int tid = threadIdx.x;
    const int bid = blockIdx.x;
    const int* srcs = edge;
    const int* dsts = edge + e;
    const int mby = (n + 63) / 64;                        // 157
    const int gw = (bid * 256 + tid) >> 6;                // global wave id
    const int nw = NB * 4;                                // total waves

    // ---- P0: zero cursor + prep ----
    {
        const int zvb = (n + 255) / 256;
        const int prep_total = n * 32 + 128 * 256 + 256 * 256 + 256 * 40
                             + 1024 + 1024 + 2048 + 2048 + 256 + 256;
        const int pvb = (prep_total + 255) / 256;
        for (int vb = bid; vb < zvb + pvb; vb += NB) {
            if (vb < zvb) {
                int i = vb * 256 + tid;
                if (i < n) cursor[i] = 0;
            } else {
                prep_body((vb - zvb) * 256 + tid, x, x_bf, W1, W1T, W2, W2T, W3, W3T,
                          as1, ad1, as2, ad2, as3, ad3, n);
            }
        }
    }
    gsync(bar, 1);

    // ---- P1: ELL scatter + layer-1 GEMM (independent) ----
    {
        const int svb = ((e + 3) / 4 + 255) / 256;
        const int gvb = 5 * mby;
        for (int vb = bid; vb < svb + gvb; vb += NB) {
            if (vb < svb) {
                scatter_body(vb, srcs, dsts, cursor, ell, e);
            } else {
                int t = vb - svb;
                gemm_body(As, Bs, x_bf, W1T, xp, als, ald, n, 256, 8, 272, 128, t % 5, t / 5);
            }
        }
    }
    gsync(bar, 2);

    // ---- P2: layer-1 aggregation ----
    for (int node = gw; node < n; node += nw)
        agg_h8_node(node, xp, als, ald, cursor, ell, b1, h_bf);
    gsync(bar, 3);

    // ---- P3: layer-2 GEMM ----
    for (int t = bid; t < 5 * mby; t += NB)
        gemm_body(As, Bs, h_bf, W2T, xp, als, ald, n, 256, 8, 272, 256, t % 5, t / 5);
    gsync(bar, 4);

    // ---- P4: layer-2 aggregation ----
    for (int node = gw; node < n; node += nw)
        agg_h8_node(node, xp, als, ald, cursor, ell, b2, h_bf);
    gsync(bar, 5);

    // ---- P5: layer-3 GEMM ----
    for (int t = bid; t < mby; t += NB)
        gemm_body(As, Bs, h_bf, W3T, xp3, als, ald, n, 40, 1, 42, 256, 0, t);
    gsync(bar, 6);

    // ---- P6: layer-3 aggregation + log_softmax ----
    for (int node = gw; node < n; node += nw)
        agg_out_node(node, xp3, als, ald, cursor, ell, b3, out);
}

// ---------------------------------------------------------------------------

extern "C" void kernel_launch(void* const* d_in, const int* in_sizes, int n_in,
                              void* d_out, int out_size, void* d_ws, size_t ws_size,
                              hipStream_t stream) {
    const float* x      = (const float*)d_in[0];
    const int*   edge   = (const int*)d_in[1];
    const float* W1     = (const float*)d_in[2];
    const float* a_src1 = (const float*)d_in[3];
    const float* a_dst1 = (const float*)d_in[4];
    const float* b1     = (const float*)d_in[5];
    const float* W2     = (const float*)d_in[6];
    const float* a_src2 = (const float*)d_in[7];
    const float* a_dst2 = (const float*)d_in[8];
    const float* b2     = (const float*)d_in[9];
    const float* W3     = (const float*)d_in[10];
    const float* a_src3 = (const float*)d_in[11];
    const float* a_dst3 = (const float*)d_in[12];
    const float* b3     = (const float*)d_in[13];
    float* out = (float*)d_out;

    const int n = in_sizes[0] / 128;   // 10000
    const int e = in_sizes[1] / 2;     // 320000

    char* ws = (char*)d_ws;
    size_t off = 0;
    auto alloc = [&](size_t bytes) -> void* {
        void* p = ws + off;
        off += (bytes + 255) & ~(size_t)255;
        return p;
    };
    ushort_t* xp        = (ushort_t*)alloc((size_t)n * 256 * 2);
    ushort_t* h_bf      = (ushort_t*)alloc((size_t)n * 256 * 2);
    ushort_t* xp3       = (ushort_t*)alloc((size_t)n * 40 * 2);
    ushort_t* x_bf      = (ushort_t*)alloc((size_t)n * 128 * 2);
    ushort_t* W1T       = (ushort_t*)alloc((size_t)272 * 128 * 2);
    ushort_t* W2T       = (ushort_t*)alloc((size_t)272 * 256 * 2);
    ushort_t* W3T       = (ushort_t*)alloc((size_t)42 * 256 * 2);
    float*    als       = (float*)alloc((size_t)n * 8 * 4);
    float*    ald       = (float*)alloc((size_t)n * 8 * 4);
    int*      cursor    = (int*)alloc((size_t)n * 4);
    int*      ell       = (int*)alloc((size_t)n * ELLW * 4);
    int*      bar       = (int*)alloc(256);
    (void)ws_size;

    // zero the barrier counter (cursor is zeroed inside P0)
    hipMemsetAsync(bar, 0, 256, stream);

    mega_kernel<<<NB, 256, 0, stream>>>(
        x, edge, W1, a_src1, a_dst1, b1, W2, a_src2, a_dst2, b2,
        W3, a_src3, a_dst3, b3, out,
        xp, h_bf, xp3, x_bf, W1T, W2T, W3T, als, ald, cursor, ell, bar, n, e);
}